// Round 5
// baseline (130.266 us; speedup 1.0000x reference)
//
#include <hip/hip_runtime.h>
#include <hip/hip_bf16.h>

// Problem constants (from reference)
constexpr int C   = 4096;   // HIDDEN_DIM
constexpr int NE  = 4;      // EXPANSION
constexpr int B   = 4096;   // batch rows
constexpr int THREADS = 512;
constexpr int PER = C / THREADS;  // 8 columns per thread
constexpr float EPSV = 1e-5f;

// Manual RNE round-to-bf16-and-back (value-based)
__device__ inline float bf16_rne(float f) {
    unsigned int u = __float_as_uint(f);
    unsigned int r = (u + 0x7FFFu + ((u >> 16) & 1u)) & 0xFFFF0000u;
    return __uint_as_float(r);
}

__global__ __launch_bounds__(THREADS)
void mhc_fused(const float* __restrict__ x,
               const float* __restrict__ w,   // rmsnorm_weight: stored as f32 on device (np has no bf16)
               const float* __restrict__ Hpre,
               const float* __restrict__ Hpost,
               const float* __restrict__ Hres,
               float* __restrict__ out) {
    const int b   = blockIdx.x;
    const int tid = threadIdx.x;
    const size_t rowbase = (size_t)b * NE * C;
    const int c0 = tid * PER;

    // ---- x: 4 streams x 8 cols, float4 vectorized, read ONCE ----
    float xs[NE][PER];
    #pragma unroll
    for (int k = 0; k < NE; ++k) {
        const float4* p = reinterpret_cast<const float4*>(x + rowbase + (size_t)k * C + c0);
        float4 a = p[0];
        float4 bq = p[1];
        xs[k][0] = a.x;  xs[k][1] = a.y;  xs[k][2] = a.z;  xs[k][3] = a.w;
        xs[k][4] = bq.x; xs[k][5] = bq.y; xs[k][6] = bq.z; xs[k][7] = bq.w;
    }

    __shared__ float sM[NE * NE];
    __shared__ float red[THREADS / 64];

    // ---- serial Sinkhorn on thread 0 (hidden under x-load latency) ----
    if (tid == 0) {
        float M[NE][NE];
        for (int i = 0; i < NE; ++i)
            for (int j = 0; j < NE; ++j)
                M[i][j] = expf(Hres[i * NE + j]);
        for (int it = 0; it < 20; ++it) {
            for (int i = 0; i < NE; ++i) {
                float rs = fmaxf(M[i][0] + M[i][1] + M[i][2] + M[i][3], EPSV);
                for (int j = 0; j < NE; ++j) M[i][j] /= rs;
            }
            for (int j = 0; j < NE; ++j) {
                float cs = fmaxf(M[0][j] + M[1][j] + M[2][j] + M[3][j], EPSV);
                for (int i = 0; i < NE; ++i) M[i][j] /= cs;
            }
        }
        for (int i = 0; i < NE; ++i)
            for (int j = 0; j < NE; ++j)
                sM[i * NE + j] = M[i][j];
    }

    // ---- gates (uniform, cheap, per-thread) ----
    const float s0 = 1.0f / (1.0f + expf(-Hpre[0]));
    const float s1 = 1.0f / (1.0f + expf(-Hpre[1]));
    const float s2 = 1.0f / (1.0f + expf(-Hpre[2]));
    const float s3 = 1.0f / (1.0f + expf(-Hpre[3]));
    float hp[NE];
    #pragma unroll
    for (int i = 0; i < NE; ++i) hp[i] = 2.0f / (1.0f + expf(-Hpost[i]));

    // ---- aggregate + bf16 RNE round + sum of squares ----
    float aggbf[PER];
    float ss = 0.0f;
    #pragma unroll
    for (int c = 0; c < PER; ++c) {
        float a = s0 * xs[0][c] + s1 * xs[1][c] + s2 * xs[2][c] + s3 * xs[3][c];
        float abf = bf16_rne(a);
        aggbf[c] = abf;
        ss += abf * abf;
    }

    // ---- block reduction (wave64 butterfly, then LDS across 8 waves) ----
    #pragma unroll
    for (int off = 32; off > 0; off >>= 1) ss += __shfl_xor(ss, off);
    const int lane = tid & 63;
    const int wid  = tid >> 6;
    if (lane == 0) red[wid] = ss;
    __syncthreads();   // also publishes sM
    float tot = 0.0f;
    #pragma unroll
    for (int i = 0; i < THREADS / 64; ++i) tot += red[i];

    const float rinv = 1.0f / sqrtf(tot * (1.0f / (float)C) + EPSV);

    // ---- rmsnorm weight: device buffer holds FLOAT32 values (f32 read, float4) ----
    float y[PER];
    {
        const float4* pw = reinterpret_cast<const float4*>(w + c0);
        float4 w0 = pw[0];
        float4 w1 = pw[1];
        y[0] = aggbf[0] * rinv * w0.x;  y[1] = aggbf[1] * rinv * w0.y;
        y[2] = aggbf[2] * rinv * w0.z;  y[3] = aggbf[3] * rinv * w0.w;
        y[4] = aggbf[4] * rinv * w1.x;  y[5] = aggbf[5] * rinv * w1.y;
        y[6] = aggbf[6] * rinv * w1.z;  y[7] = aggbf[7] * rinv * w1.w;
    }

    // ---- Sinkhorn matrix from LDS (uniform broadcast) ----
    float M[NE][NE];
    #pragma unroll
    for (int i = 0; i < NE; ++i)
        #pragma unroll
        for (int j = 0; j < NE; ++j)
            M[i][j] = sM[i * NE + j];

    // ---- outputs: out[b,i,c] = sum_j M[i][j]*x[b,j,c] + hp[i]*y[c] ----
    #pragma unroll
    for (int i = 0; i < NE; ++i) {
        float o[PER];
        #pragma unroll
        for (int c = 0; c < PER; ++c) {
            o[c] = M[i][0] * xs[0][c] + M[i][1] * xs[1][c]
                 + M[i][2] * xs[2][c] + M[i][3] * xs[3][c]
                 + hp[i] * y[c];
        }
        float4* po = reinterpret_cast<float4*>(out + rowbase + (size_t)i * C + c0);
        po[0] = make_float4(o[0], o[1], o[2], o[3]);
        po[1] = make_float4(o[4], o[5], o[6], o[7]);
    }
}

extern "C" void kernel_launch(void* const* d_in, const int* in_sizes, int n_in,
                              void* d_out, int out_size, void* d_ws, size_t ws_size,
                              hipStream_t stream) {
    const float* x     = (const float*)d_in[0];
    const float* w     = (const float*)d_in[1];   // read as f32 (see theory)
    const float* Hpre  = (const float*)d_in[2];
    const float* Hpost = (const float*)d_in[3];
    const float* Hres  = (const float*)d_in[4];
    float* out         = (float*)d_out;

    mhc_fused<<<B, THREADS, 0, stream>>>(x, w, Hpre, Hpost, Hres, out);
}

// Round 6
// 113.056 us; speedup vs baseline: 1.1522x; 1.1522x over previous
//
#include <hip/hip_runtime.h>
#include <hip/hip_bf16.h>

// Problem constants (from reference)
constexpr int C   = 4096;   // HIDDEN_DIM
constexpr int NE  = 4;      // EXPANSION
constexpr int B   = 4096;   // batch rows
constexpr int THREADS = 512;
constexpr int PER = C / THREADS;  // 8 columns per thread
constexpr float EPSV = 1e-5f;

// Manual RNE round-to-bf16-and-back (value-based)
__device__ inline float bf16_rne(float f) {
    unsigned int u = __float_as_uint(f);
    unsigned int r = (u + 0x7FFFu + ((u >> 16) & 1u)) & 0xFFFF0000u;
    return __uint_as_float(r);
}

// ---- prep kernel (1 block): Sinkhorn(4x4) lane-parallel + sigmoid gates -> ws ----
// ws layout: [0..15] = M row-major, [16..19] = sigmoid(H_pre), [20..23] = 2*sigmoid(H_post)
__global__ void mhc_prep(const float* __restrict__ Hpre,
                         const float* __restrict__ Hpost,
                         const float* __restrict__ Hres,
                         float* __restrict__ ws) {
    const int l = threadIdx.x;   // one wave
    // lane l<16 holds M[i][j], i=l>>2, j=l&3
    float m = (l < 16) ? expf(Hres[l]) : 0.0f;
    for (int it = 0; it < 20; ++it) {
        float r = m + __shfl_xor(m, 1);      // sum over j (xor 1,2 stays in row group)
        r += __shfl_xor(r, 2);
        m /= fmaxf(r, EPSV);
        float cs = m + __shfl_xor(m, 4);     // sum over i (xor 4,8)
        cs += __shfl_xor(cs, 8);
        m /= fmaxf(cs, EPSV);
    }
    if (l < 16) ws[l] = m;
    if (l < NE) {
        ws[16 + l] = 1.0f / (1.0f + expf(-Hpre[l]));
        ws[20 + l] = 2.0f / (1.0f + expf(-Hpost[l]));
    }
}

// ---- main kernel: pure streaming, one block per row ----
__global__ __launch_bounds__(THREADS)
void mhc_main(const float* __restrict__ x,
              const float* __restrict__ w,   // rmsnorm_weight stored as f32 on device
              const float* __restrict__ ws,
              float* __restrict__ out) {
    const int b   = blockIdx.x;
    const int tid = threadIdx.x;
    const size_t rowbase = (size_t)b * NE * C;
    const int c0 = tid * PER;

    // ---- x: 4 streams x 8 cols, float4 vectorized, read ONCE ----
    float xs[NE][PER];
    #pragma unroll
    for (int k = 0; k < NE; ++k) {
        const float4* p = reinterpret_cast<const float4*>(x + rowbase + (size_t)k * C + c0);
        float4 a = p[0];
        float4 bq = p[1];
        xs[k][0] = a.x;  xs[k][1] = a.y;  xs[k][2] = a.z;  xs[k][3] = a.w;
        xs[k][4] = bq.x; xs[k][5] = bq.y; xs[k][6] = bq.z; xs[k][7] = bq.w;
    }

    // ---- precomputed constants (uniform scalar loads, L2-broadcast) ----
    const float s0 = ws[16], s1 = ws[17], s2 = ws[18], s3 = ws[19];
    float hp[NE];
    #pragma unroll
    for (int i = 0; i < NE; ++i) hp[i] = ws[20 + i];
    float M[NE][NE];
    #pragma unroll
    for (int i = 0; i < NE; ++i)
        #pragma unroll
        for (int j = 0; j < NE; ++j)
            M[i][j] = ws[i * NE + j];

    // ---- aggregate + bf16 RNE round + sum of squares ----
    float aggbf[PER];
    float ss = 0.0f;
    #pragma unroll
    for (int c = 0; c < PER; ++c) {
        float a = s0 * xs[0][c] + s1 * xs[1][c] + s2 * xs[2][c] + s3 * xs[3][c];
        float abf = bf16_rne(a);
        aggbf[c] = abf;
        ss += abf * abf;
    }

    // ---- block reduction (wave64 butterfly, then LDS across 8 waves) ----
    #pragma unroll
    for (int off = 32; off > 0; off >>= 1) ss += __shfl_xor(ss, off);
    __shared__ float red[THREADS / 64];
    const int lane = tid & 63;
    const int wid  = tid >> 6;
    if (lane == 0) red[wid] = ss;
    __syncthreads();
    float tot = 0.0f;
    #pragma unroll
    for (int i = 0; i < THREADS / 64; ++i) tot += red[i];

    const float rinv = 1.0f / sqrtf(tot * (1.0f / (float)C) + EPSV);

    // ---- y = aggbf * rinv * w  (w is f32 on device; float4 loads) ----
    float y[PER];
    {
        const float4* pw = reinterpret_cast<const float4*>(w + c0);
        float4 w0 = pw[0];
        float4 w1 = pw[1];
        y[0] = aggbf[0] * rinv * w0.x;  y[1] = aggbf[1] * rinv * w0.y;
        y[2] = aggbf[2] * rinv * w0.z;  y[3] = aggbf[3] * rinv * w0.w;
        y[4] = aggbf[4] * rinv * w1.x;  y[5] = aggbf[5] * rinv * w1.y;
        y[6] = aggbf[6] * rinv * w1.z;  y[7] = aggbf[7] * rinv * w1.w;
    }

    // ---- outputs: out[b,i,c] = sum_j M[i][j]*x[b,j,c] + hp[i]*y[c] ----
    #pragma unroll
    for (int i = 0; i < NE; ++i) {
        float o[PER];
        #pragma unroll
        for (int c = 0; c < PER; ++c) {
            o[c] = M[i][0] * xs[0][c] + M[i][1] * xs[1][c]
                 + M[i][2] * xs[2][c] + M[i][3] * xs[3][c]
                 + hp[i] * y[c];
        }
        float4* po = reinterpret_cast<float4*>(out + rowbase + (size_t)i * C + c0);
        po[0] = make_float4(o[0], o[1], o[2], o[3]);
        po[1] = make_float4(o[4], o[5], o[6], o[7]);
    }
}

extern "C" void kernel_launch(void* const* d_in, const int* in_sizes, int n_in,
                              void* d_out, int out_size, void* d_ws, size_t ws_size,
                              hipStream_t stream) {
    const float* x     = (const float*)d_in[0];
    const float* w     = (const float*)d_in[1];   // f32 on device (np has no bf16)
    const float* Hpre  = (const float*)d_in[2];
    const float* Hpost = (const float*)d_in[3];
    const float* Hres  = (const float*)d_in[4];
    float* out         = (float*)d_out;
    float* ws          = (float*)d_ws;

    mhc_prep<<<1, 64, 0, stream>>>(Hpre, Hpost, Hres, ws);
    mhc_main<<<B, THREADS, 0, stream>>>(x, w, ws, out);
}